// Round 1
// baseline (2673.002 us; speedup 1.0000x reference)
//
#include <hip/hip_runtime.h>
#include <cfloat>

// Problem constants (match reference)
constexpr int Bn = 1024, Ln = 1024, Vn = 20, Dn = 128;

// v mod 20 for 0 <= v <= ~1000 (magic multiply, exact in this range)
__device__ __forceinline__ int mod20(int v) { return v - 20 * ((v * 205) >> 12); }

__global__ __launch_bounds__(64, 1) void daf_chain(
    const float* __restrict__ x, const float* __restrict__ emb,
    const float* __restrict__ W, const float* __restrict__ bvec,
    float* __restrict__ out)
{
  __shared__ double state64[Dn];          // broadcast copy of state, f64
  __shared__ float  embs[Vn * Dn];        // emb rows, f32
  __shared__ unsigned char aidx[Ln];      // input token index per step

  const int lane  = threadIdx.x;
  const int batch = blockIdx.x;

  // Lane -> output column mapping: lanes 0..19 -> j=0..19 (loc group, lanes 0..31),
  // lanes 32..51 -> j=20..39 (scale group, lanes 32..63). Others inactive.
  const bool active = (lane < Vn) || (lane >= 32 && lane < 32 + Vn);
  const int  jm     = (lane < 32) ? lane : (lane - 32 + Vn);

  // Per-lane W column in f64 registers (static indices only -> stays in VGPRs)
  double wcol[Dn];
  if (active) {
#pragma unroll
    for (int d = 0; d < Dn; ++d) wcol[d] = (double)W[d * (2 * Vn) + jm];
  } else {
#pragma unroll
    for (int d = 0; d < Dn; ++d) wcol[d] = 0.0;
  }
  const double bj = active ? (double)bvec[jm] : 0.0;

  // Stage emb into LDS (coalesced)
  for (int i = lane; i < Vn * Dn; i += 64) embs[i] = emb[i];

  // Extract this batch's token indices from the one-hot x (coalesced reads)
  const float* xb = x + (size_t)batch * Ln * Vn;
  for (int i = lane; i < Ln * Vn; i += 64) {
    if (xb[i] > 0.5f) aidx[i / Vn] = (unsigned char)(i % Vn);
  }

  // Init state: f32 master copy lives in registers (lane owns d=lane and d=lane+64),
  // f64 broadcast copy in LDS.
  state64[lane]      = 0.0;
  state64[lane + 64] = 0.0;
  float s32a = 0.0f, s32b = 0.0f;

  __syncthreads();

  float* outb = out + (size_t)batch * Ln * Vn;

  for (int t = 0; t < Ln; ++t) {
    const int a = (int)aidx[t];  // issued early; latency hides under the dot

    // net_j = sum_d state[d] * W[d][j]  in f64 (products exact, sum ~1e-16)
    double acc0 = 0.0, acc1 = 0.0, acc2 = 0.0, acc3 = 0.0;
#pragma unroll
    for (int d = 0; d < Dn; d += 4) {
      acc0 = __builtin_fma(state64[d + 0], wcol[d + 0], acc0);
      acc1 = __builtin_fma(state64[d + 1], wcol[d + 1], acc1);
      acc2 = __builtin_fma(state64[d + 2], wcol[d + 2], acc2);
      acc3 = __builtin_fma(state64[d + 3], wcol[d + 3], acc3);
    }
    const double net = ((acc0 + acc1) + (acc2 + acc3)) + bj;

    // Two width-32 argmax butterflies (loc in lanes 0..31, scale in lanes 32..63).
    // Tie-break: smaller index (matches jnp.argmax first-max semantics).
    double v = active ? net : -DBL_MAX;
    int idx = jm;
#pragma unroll
    for (int off = 16; off >= 1; off >>= 1) {
      double ov = __shfl_xor(v, off);
      int    oi = __shfl_xor(idx, off);
      const bool take = (ov > v) || (ov == v && oi < idx);
      v   = take ? ov : v;
      idx = take ? oi : idx;
    }
    const int loc   = __shfl(idx, 0);        // in 0..19
    const int scale = __shfl(idx, 32) - Vn;  // in 0..19

    // out_idx = (inv20(scale) * ((a - loc) mod 20)) mod 20, all in registers
    int r = a - loc; r += (r >> 31) & Vn;    // (a - loc) mod 20
    const int s  = scale;
    const int s2 = mod20(s * s);
    const int s4 = mod20(s2 * s2);
    const int s6 = mod20(s4 * s2);
    int inv = mod20(s6 * s);                 // s^7 mod 20 (= s^-1 for coprime s)
    const bool cop = ((s & 1) != 0) && ((s - 5 * ((s * 205) >> 10)) != 0);
    inv = cop ? inv : 0;                     // non-coprime -> INV_P row = e_0
    const int oidx = mod20(inv * r);

    // Write one-hot output row (one 80B wave store)
    if (lane < Vn) outb[(size_t)t * Vn + lane] = (lane == oidx) ? 1.0f : 0.0f;

    // Exact fp32 state walk: one rounded add per component, bit-reproducible.
    {
      const float e0 = embs[oidx * Dn + lane];
      const float e1 = embs[oidx * Dn + lane + 64];
      s32a += e0;
      s32b += e1;
      state64[lane]      = (double)s32a;
      state64[lane + 64] = (double)s32b;
    }
    __syncthreads();  // order state64 writes before next iteration's reads
  }
}

extern "C" void kernel_launch(void* const* d_in, const int* in_sizes, int n_in,
                              void* d_out, int out_size, void* d_ws, size_t ws_size,
                              hipStream_t stream) {
  const float* x   = (const float*)d_in[0];
  const float* emb = (const float*)d_in[1];
  const float* W   = (const float*)d_in[2];
  const float* b   = (const float*)d_in[3];
  float* out = (float*)d_out;
  hipLaunchKernelGGL(daf_chain, dim3(Bn), dim3(64), 0, stream,
                     x, emb, W, b, out);
}